// Round 3
// baseline (25257.008 us; speedup 1.0000x reference)
//
#include <hip/hip_runtime.h>
#include <math.h>

#define T_LEN 4096
#define HID   1024
#define G4    4096
#define KTAG  50
#define KPAD  64
#define START_TAG 48
#define END_TAG   49

// ---------------- workspace layout (float-element offsets) ----------------
#define XG_OFF     ((size_t)0)                        // [2][T][4096] f32
#define XG_SZ      ((size_t)2*T_LEN*G4)
#define HOUT_OFF   (XG_OFF + XG_SZ)                   // [2][T][1024] f32
#define HOUT_SZ    ((size_t)2*T_LEN*HID)
#define WT_OFF     (HOUT_OFF + HOUT_SZ)               // [2048][64] f32
#define WT_SZ      ((size_t)2*HID*KPAD)
#define FEATS_OFF  (WT_OFF + WT_SZ)                   // [T][64] f32
#define FEATS_SZ   ((size_t)T_LEN*KPAD)
#define BP_OFF     (FEATS_OFF + FEATS_SZ)             // [T][64] i32
#define BP_SZ      ((size_t)T_LEN*KPAD)
#define MMAP_OFF   (BP_OFF + BP_SZ)                   // [64][64] i32
#define MMAP_SZ    ((size_t)64*64)
#define ENTRY_OFF  (MMAP_OFF + MMAP_SZ)               // [64] i32
#define BEST_OFF   (ENTRY_OFF + 64)                   // [1] i32
// seq-fused h transport: [2 slots][2 dirs][1024] u64 (32 KB), 8B-aligned
#define HSEQ_OFF   (((BEST_OFF + 1) + 15) & ~(size_t)15)
#define HSEQ_SZ    ((size_t)8192)                     // in floats (4096 u64)
#define WS_NEEDED  (((HSEQ_OFF + HSEQ_SZ) * 4))

// =========================================================================
// 1) xg[d][t][r] = sum_h X[t][h]*W_ih[d][r][h] + b_ih[r] + b_hh[r]
// =========================================================================
__global__ __launch_bounds__(256, 2) void gemm_xg(
    const float* __restrict__ X, const float* __restrict__ Wf, const float* __restrict__ Wb,
    const float* __restrict__ bihf, const float* __restrict__ bhhf,
    const float* __restrict__ bihb, const float* __restrict__ bhhb,
    float* __restrict__ xg)
{
  const int d  = blockIdx.z;
  const float* __restrict__ W = d ? Wb : Wf;
  const int r0 = blockIdx.x * 64;
  const int t0 = blockIdx.y * 64;
  __shared__ float Xs[16][68];
  __shared__ float Ws[16][68];
  const int tid = threadIdx.x;
  const int tx = tid & 15, ty = tid >> 4;
  const int srow = tid >> 2, skq = (tid & 3) * 4;

  float acc[4][4];
#pragma unroll
  for (int i = 0; i < 4; ++i)
#pragma unroll
    for (int j = 0; j < 4; ++j) acc[i][j] = 0.f;

#pragma unroll 1
  for (int k0 = 0; k0 < HID; k0 += 16) {
    const float4 xv = *(const float4*)&X[(size_t)(t0 + srow) * HID + k0 + skq];
    const float4 wv = *(const float4*)&W[(size_t)(r0 + srow) * HID + k0 + skq];
    __syncthreads();
    Xs[skq + 0][srow] = xv.x; Xs[skq + 1][srow] = xv.y; Xs[skq + 2][srow] = xv.z; Xs[skq + 3][srow] = xv.w;
    Ws[skq + 0][srow] = wv.x; Ws[skq + 1][srow] = wv.y; Ws[skq + 2][srow] = wv.z; Ws[skq + 3][srow] = wv.w;
    __syncthreads();
#pragma unroll
    for (int kk = 0; kk < 16; ++kk) {
      const float4 av = *(const float4*)&Xs[kk][ty * 4];
      const float4 bv = *(const float4*)&Ws[kk][tx * 4];
      acc[0][0] += av.x * bv.x; acc[0][1] += av.x * bv.y; acc[0][2] += av.x * bv.z; acc[0][3] += av.x * bv.w;
      acc[1][0] += av.y * bv.x; acc[1][1] += av.y * bv.y; acc[1][2] += av.y * bv.z; acc[1][3] += av.y * bv.w;
      acc[2][0] += av.z * bv.x; acc[2][1] += av.z * bv.y; acc[2][2] += av.z * bv.z; acc[2][3] += av.z * bv.w;
      acc[3][0] += av.w * bv.x; acc[3][1] += av.w * bv.y; acc[3][2] += av.w * bv.z; acc[3][3] += av.w * bv.w;
    }
  }
  const float* __restrict__ b1 = d ? bihb : bihf;
  const float* __restrict__ b2 = d ? bhhb : bhhf;
  float bias[4];
#pragma unroll
  for (int j = 0; j < 4; ++j) bias[j] = b1[r0 + tx * 4 + j] + b2[r0 + tx * 4 + j];
#pragma unroll
  for (int i = 0; i < 4; ++i) {
    float4 v;
    v.x = acc[i][0] + bias[0]; v.y = acc[i][1] + bias[1];
    v.z = acc[i][2] + bias[2]; v.w = acc[i][3] + bias[3];
    *(float4*)&xg[((size_t)d * T_LEN + t0 + ty * 4 + i) * G4 + r0 + tx * 4] = v;
  }
}

// =========================================================================
// 2) Persistent bidirectional LSTM recurrence — seq-fused single-RT transport.
//    h travels as u64 {seq=it+1 (hi32), f32 bits (lo32)} through the
//    coherence point via AGENT-scope relaxed atomics, depth-2 ring.
//    Producer: 8 packed stores, NO ack wait, NO flag. Consumer: polls its
//    own 4 u64s; payload arrives with the seq -> one L3 round trip total.
//    Ring-2 safety: a producer reaches iter it only after all WGs published
//    it-1, which implies all reads of the slot being overwritten completed.
// =========================================================================
__global__ __launch_bounds__(256, 1) void lstm_rec(
    const float* __restrict__ xg, const float* __restrict__ whhf,
    const float* __restrict__ whhb, float* __restrict__ hout,
    unsigned long long* __restrict__ hseq)
{
  const int g = blockIdx.x;
  const int d = g >> 7;
  const int s = g & 127;
  const float* __restrict__ whh = d ? whhb : whhf;
  const int tid = threadIdx.x;
  const int sub = tid & 15;   // column group: cols [sub*64, sub*64+64)
  const int rp  = tid >> 4;   // local rows rp and rp+16

  const int lr0 = rp, lr1 = rp + 16;
  const int r0 = ((lr0 >> 3) << 10) + (s << 3) + (lr0 & 7);
  const int r1 = ((lr1 >> 3) << 10) + (s << 3) + (lr1 & 7);

  float w0[64], w1[64];
  {
    const float4* p0 = (const float4*)(whh + (size_t)r0 * HID + sub * 64);
    const float4* p1 = (const float4*)(whh + (size_t)r1 * HID + sub * 64);
#pragma unroll
    for (int b = 0; b < 16; ++b) {
      const float4 v = p0[b];
      w0[4 * b + 0] = v.x; w0[4 * b + 1] = v.y; w0[4 * b + 2] = v.z; w0[4 * b + 3] = v.w;
      const float4 u = p1[b];
      w1[4 * b + 0] = u.x; w1[4 * b + 1] = u.y; w1[4 * b + 2] = u.z; w1[4 * b + 3] = u.w;
    }
  }

  __shared__ float hs[1024];   // swizzled h staging
  __shared__ float gl[32];
  __shared__ int   abortf[1];
  if (tid == 0) abortf[0] = 0;
  float creg = 0.f;            // cell state (used by tid<8 only)
  __syncthreads();

  const float* __restrict__ xgd = xg + (size_t)d * T_LEN * G4;
  // staging slot: element h[G*64+B*4+i] lives at hs[G*64 + ((B+G)&15)*4 + i]
  const int stG = tid >> 4, stB = tid & 15;
  const int stOff = (stG << 6) + ((((stB) + stG) & 15) << 2);

#pragma unroll 1
  for (int it = 0; it < T_LEN; ++it) {
    const int t = d ? (T_LEN - 1 - it) : it;
    float xg0 = 0.f, xg1 = 0.f;
    if (sub == 0) {  // prefetch gate-precompute terms early (hides under poll)
      const float* xr = xgd + (size_t)t * G4;
      xg0 = xr[r0]; xg1 = xr[r1];
    }

    if (it > 0) {
      const unsigned long long* hp =
          hseq + ((((size_t)((it - 1) & 1)) * 2 + d) << 10) + (tid << 2);
      const unsigned target = (unsigned)it;  // producers at it-1 stored seq=it
      unsigned long long q0, q1, q2, q3;
      int guard = 1 << 16;
      for (;;) {
        q0 = __hip_atomic_load(hp + 0, __ATOMIC_RELAXED, __HIP_MEMORY_SCOPE_AGENT);
        q1 = __hip_atomic_load(hp + 1, __ATOMIC_RELAXED, __HIP_MEMORY_SCOPE_AGENT);
        q2 = __hip_atomic_load(hp + 2, __ATOMIC_RELAXED, __HIP_MEMORY_SCOPE_AGENT);
        q3 = __hip_atomic_load(hp + 3, __ATOMIC_RELAXED, __HIP_MEMORY_SCOPE_AGENT);
        if ((unsigned)(q0 >> 32) == target && (unsigned)(q1 >> 32) == target &&
            (unsigned)(q2 >> 32) == target && (unsigned)(q3 >> 32) == target) break;
        if (--guard == 0) { abortf[0] = 1; break; }
      }
      float4 hv;
      hv.x = __builtin_bit_cast(float, (unsigned)(q0 & 0xffffffffu));
      hv.y = __builtin_bit_cast(float, (unsigned)(q1 & 0xffffffffu));
      hv.z = __builtin_bit_cast(float, (unsigned)(q2 & 0xffffffffu));
      hv.w = __builtin_bit_cast(float, (unsigned)(q3 & 0xffffffffu));
      *(float4*)&hs[stOff] = hv;
    } else {
      *(float4*)&hs[stOff] = make_float4(0.f, 0.f, 0.f, 0.f);
    }
    __syncthreads();
    if (abortf[0] != 0) break;   // uniform: bail instead of hanging forever

    // reg-resident GEMV: 2 rows x 64 cols per lane, 4 acc chains for ILP
    float a0e = 0.f, a0o = 0.f, a1e = 0.f, a1o = 0.f;
#pragma unroll
    for (int b = 0; b < 16; ++b) {
      const float4 h4 = *(const float4*)&hs[(sub << 6) + (((b + sub) & 15) << 2)];
      if ((b & 1) == 0) {
        a0e += h4.x * w0[4 * b + 0]; a0e += h4.y * w0[4 * b + 1];
        a0e += h4.z * w0[4 * b + 2]; a0e += h4.w * w0[4 * b + 3];
        a1e += h4.x * w1[4 * b + 0]; a1e += h4.y * w1[4 * b + 1];
        a1e += h4.z * w1[4 * b + 2]; a1e += h4.w * w1[4 * b + 3];
      } else {
        a0o += h4.x * w0[4 * b + 0]; a0o += h4.y * w0[4 * b + 1];
        a0o += h4.z * w0[4 * b + 2]; a0o += h4.w * w0[4 * b + 3];
        a1o += h4.x * w1[4 * b + 0]; a1o += h4.y * w1[4 * b + 1];
        a1o += h4.z * w1[4 * b + 2]; a1o += h4.w * w1[4 * b + 3];
      }
    }
    float a0 = a0e + a0o, a1 = a1e + a1o;
#pragma unroll
    for (int m = 1; m < 16; m <<= 1) { a0 += __shfl_xor(a0, m); a1 += __shfl_xor(a1, m); }
    if (sub == 0) { gl[rp] = a0 + xg0; gl[rp + 16] = a1 + xg1; }
    __syncthreads();

    if (tid < 8) {
      const float gi = gl[tid], gf = gl[8 + tid], gg = gl[16 + tid], go = gl[24 + tid];
      const float ii = 1.f / (1.f + expf(-gi));
      const float ff = 1.f / (1.f + expf(-gf));
      const float oo = 1.f / (1.f + expf(-go));
      creg = ff * creg + ii * tanhf(gg);
      const float h = oo * tanhf(creg);
      hout[((size_t)d * T_LEN + t) * HID + (s << 3) + tid] = h;  // plain (for dense)
      const unsigned long long pkt =
          ((unsigned long long)(unsigned)(it + 1) << 32) |
          (unsigned long long)__builtin_bit_cast(unsigned, h);
      __hip_atomic_store(hseq + ((((size_t)(it & 1)) * 2 + d) << 10) + (s << 3) + tid,
                         pkt, __ATOMIC_RELAXED, __HIP_MEMORY_SCOPE_AGENT);
    }
  }
}

// =========================================================================
// 3) dense_w transpose and feats GEMM
// =========================================================================
__global__ void transpose_w(const float* __restrict__ dw, float* __restrict__ WT) {
  const int i = blockIdx.x * 256 + threadIdx.x;
  if (i < KTAG * 2 * HID) {
    const int k = i / (2 * HID), h = i % (2 * HID);
    WT[(size_t)h * KPAD + k] = dw[i];
  }
}

__global__ __launch_bounds__(256, 2) void dense_kernel(
    const float* __restrict__ hout, const float* __restrict__ WT,
    const float* __restrict__ db, float* __restrict__ feats)
{
  __shared__ float hrow[4][2048];
  const int tid = threadIdx.x, w = tid >> 6, l = tid & 63;
  const int t = blockIdx.x * 4 + w;
  const float* hf = hout + (size_t)t * HID;
  const float* hb = hout + ((size_t)T_LEN + t) * HID;
#pragma unroll
  for (int c = 0; c < 4; ++c)
    *(float4*)&hrow[w][c * 256 + l * 4] = *(const float4*)&hf[c * 256 + l * 4];
#pragma unroll
  for (int c = 0; c < 4; ++c)
    *(float4*)&hrow[w][1024 + c * 256 + l * 4] = *(const float4*)&hb[c * 256 + l * 4];
  __syncthreads();
  float acc = (l < KTAG) ? db[l] : 0.f;
#pragma unroll 4
  for (int h = 0; h < 2 * HID; h += 4) {
    const float4 hv = *(const float4*)&hrow[w][h];
    acc += hv.x * WT[(size_t)(h + 0) * KPAD + l];
    acc += hv.y * WT[(size_t)(h + 1) * KPAD + l];
    acc += hv.z * WT[(size_t)(h + 2) * KPAD + l];
    acc += hv.w * WT[(size_t)(h + 3) * KPAD + l];
  }
  if (l < KTAG) feats[(size_t)t * KPAD + l] = acc;
}

// =========================================================================
// 4) Viterbi forward scan — single wave (64 threads), exact first-index
//    argmax semantics (ascending p, strict >), 53-stride conflict-free tile.
// =========================================================================
__global__ __launch_bounds__(64, 1) void viterbi_fwd(
    const float* __restrict__ feats, const float* __restrict__ trans,
    int* __restrict__ bp, float* __restrict__ out, int* __restrict__ best)
{
  __shared__ float tl[KTAG * 53];
  __shared__ float fvs[64];
  const int l = threadIdx.x;
  for (int i = l; i < KTAG * KTAG; i += 64) tl[(i / KTAG) * 53 + (i % KTAG)] = trans[i];
  fvs[l] = (l == START_TAG) ? 0.f : -10000.f;
  __syncthreads();

  float ftc = (l < KTAG) ? feats[l] : 0.f;
#pragma unroll 1
  for (int t = 0; t < T_LEN; ++t) {
    float ftn = 0.f;
    if (t + 1 < T_LEN && l < KTAG) ftn = feats[(size_t)(t + 1) * KPAD + l];
    float m = -3.4e38f; int a = 0;
    if (l < KTAG) {
#pragma unroll 1
      for (int p = 0; p < KTAG; ++p) {
        const float v = tl[l * 53 + p] + fvs[p];
        if (v > m) { m = v; a = p; }
      }
      bp[(size_t)t * KPAD + l] = a;
    }
    __syncthreads();
    fvs[l] = (l < KTAG) ? m + ftc : -10000.f;
    ftc = ftn;
    __syncthreads();
  }

  float bv = -3.4e38f; int bi = 1 << 20;
  if (l < KTAG) { bv = fvs[l] + tl[END_TAG * 53 + l]; bi = l; }
#pragma unroll
  for (int m = 1; m < 64; m <<= 1) {
    const float ov = __shfl_xor(bv, m);
    const int   oi = __shfl_xor(bi, m);
    if (ov > bv || (ov == bv && oi < bi)) { bv = ov; bi = oi; }
  }
  if (l == 0) { out[0] = bv; best[0] = bi; }
}

// =========================================================================
// 5) Backtrack via per-chunk map composition (64 chunks of 64 steps)
// =========================================================================
__global__ void bt_chunk(const int* __restrict__ bp, int* __restrict__ mmap) {
  const int c = blockIdx.x, l = threadIdx.x;
  if (l < KTAG) {
    int x = l;
    for (int t = c * 64 + 63; t >= c * 64; --t) x = bp[(size_t)t * KPAD + x];
    mmap[c * 64 + l] = x;
  }
}

__global__ void bt_stitch(const int* __restrict__ mmap, const int* __restrict__ best,
                          int* __restrict__ entry) {
  __shared__ int ml[64 * 64];
  const int tid = threadIdx.x;
  for (int c = 0; c < 64; ++c) ml[c * 64 + tid] = mmap[c * 64 + tid];
  __syncthreads();
  if (tid == 0) {
    int e = best[0];
    for (int c = 63; c >= 0; --c) { entry[c] = e; e = ml[c * 64 + e]; }
  }
}

__global__ void bt_fill(const int* __restrict__ bp, const int* __restrict__ entry,
                        float* __restrict__ out) {
  const int c = blockIdx.x;
  if (threadIdx.x == 0) {
    int x = entry[c];                    // tag at t = c*64+63
    out[1 + c * 64 + 63] = (float)x;
    for (int t = c * 64 + 63; t > c * 64; --t) {
      x = bp[(size_t)t * KPAD + x];
      out[1 + t - 1] = (float)x;
    }
  }
}

// =========================================================================
extern "C" void kernel_launch(void* const* d_in, const int* in_sizes, int n_in,
                              void* d_out, int out_size, void* d_ws, size_t ws_size,
                              hipStream_t stream) {
  (void)in_sizes; (void)n_in; (void)out_size;
  const float* sent  = (const float*)d_in[0];
  const float* wihf  = (const float*)d_in[1];
  const float* whhf  = (const float*)d_in[2];
  const float* bihf  = (const float*)d_in[3];
  const float* bhhf  = (const float*)d_in[4];
  const float* wihb  = (const float*)d_in[5];
  const float* whhb  = (const float*)d_in[6];
  const float* bihb  = (const float*)d_in[7];
  const float* bhhb  = (const float*)d_in[8];
  const float* dw    = (const float*)d_in[9];
  const float* db    = (const float*)d_in[10];
  const float* trans = (const float*)d_in[11];

  if (ws_size < WS_NEEDED) return;
  float* ws    = (float*)d_ws;
  float* xg    = ws + XG_OFF;
  float* hout  = ws + HOUT_OFF;
  float* WT    = ws + WT_OFF;
  float* feats = ws + FEATS_OFF;
  int*   bp    = (int*)(ws + BP_OFF);
  int*   mmap  = (int*)(ws + MMAP_OFF);
  int*   entry = (int*)(ws + ENTRY_OFF);
  int*   best  = (int*)(ws + BEST_OFF);
  unsigned long long* hseq = (unsigned long long*)(ws + HSEQ_OFF);
  float* out = (float*)d_out;

  // zero the 32 KB transport ring: seq targets are >=1, so zeros are inert;
  // keeps every graph replay stale-state-free.
  hipMemsetAsync(hseq, 0, HSEQ_SZ * 4, stream);

  hipLaunchKernelGGL(gemm_xg, dim3(64, 64, 2), dim3(256), 0, stream,
                     sent, wihf, wihb, bihf, bhhf, bihb, bhhb, xg);
  hipLaunchKernelGGL(transpose_w, dim3((KTAG * 2 * HID + 255) / 256), dim3(256), 0, stream,
                     dw, WT);
  {
    const float* a0 = xg; const float* a1 = whhf; const float* a2 = whhb;
    float* a3 = hout; unsigned long long* a4 = hseq;
    void* args[] = { (void*)&a0, (void*)&a1, (void*)&a2, (void*)&a3, (void*)&a4 };
    hipError_t ce = hipLaunchCooperativeKernel((void*)lstm_rec, dim3(256), dim3(256),
                                               args, 0, stream);
    if (ce != hipSuccess) {
      hipLaunchKernelGGL(lstm_rec, dim3(256), dim3(256), 0, stream, a0, a1, a2, a3, a4);
    }
  }
  hipLaunchKernelGGL(dense_kernel, dim3(T_LEN / 4), dim3(256), 0, stream, hout, WT, db, feats);
  hipLaunchKernelGGL(viterbi_fwd, dim3(1), dim3(64), 0, stream, feats, trans, bp, out, best);
  hipLaunchKernelGGL(bt_chunk, dim3(64), dim3(64), 0, stream, bp, mmap);
  hipLaunchKernelGGL(bt_stitch, dim3(1), dim3(64), 0, stream, mmap, best, entry);
  hipLaunchKernelGGL(bt_fill, dim3(64), dim3(64), 0, stream, bp, entry, out);
}

// Round 4
// 17419.633 us; speedup vs baseline: 1.4499x; 1.4499x over previous
//
#include <hip/hip_runtime.h>
#include <math.h>

#define T_LEN 4096
#define HID   1024
#define G4    4096
#define KTAG  50
#define KPAD  64
#define START_TAG 48
#define END_TAG   49

// ---------------- workspace layout (float-element offsets) ----------------
#define XG_OFF     ((size_t)0)                        // [2][T][4096] f32
#define XG_SZ      ((size_t)2*T_LEN*G4)
#define HOUT_OFF   (XG_OFF + XG_SZ)                   // [2][T][1024] f32
#define HOUT_SZ    ((size_t)2*T_LEN*HID)
#define WT_OFF     (HOUT_OFF + HOUT_SZ)               // [2048][64] f32
#define WT_SZ      ((size_t)2*HID*KPAD)
#define FEATS_OFF  (WT_OFF + WT_SZ)                   // [T][64] f32
#define FEATS_SZ   ((size_t)T_LEN*KPAD)
#define BP_OFF     (FEATS_OFF + FEATS_SZ)             // [T][64] i32
#define BP_SZ      ((size_t)T_LEN*KPAD)
#define MMAP_OFF   (BP_OFF + BP_SZ)                   // [64][64] i32
#define MMAP_SZ    ((size_t)64*64)
#define ENTRY_OFF  (MMAP_OFF + MMAP_SZ)               // [64] i32
#define BEST_OFF   (ENTRY_OFF + 64)                   // [1] i32
// seq-fused h transport: [2 slots][2 dirs][1024] u64 (32 KB), 8B-aligned
#define HSEQ_OFF   (((BEST_OFF + 1) + 15) & ~(size_t)15)
#define HSEQ_SZ    ((size_t)8192)                     // in floats (4096 u64)
#define WS_NEEDED  (((HSEQ_OFF + HSEQ_SZ) * 4))

// =========================================================================
// 1) xg[d][t][r] = sum_h X[t][h]*W_ih[d][r][h] + b_ih[r] + b_hh[r]
// =========================================================================
__global__ __launch_bounds__(256, 2) void gemm_xg(
    const float* __restrict__ X, const float* __restrict__ Wf, const float* __restrict__ Wb,
    const float* __restrict__ bihf, const float* __restrict__ bhhf,
    const float* __restrict__ bihb, const float* __restrict__ bhhb,
    float* __restrict__ xg)
{
  const int d  = blockIdx.z;
  const float* __restrict__ W = d ? Wb : Wf;
  const int r0 = blockIdx.x * 64;
  const int t0 = blockIdx.y * 64;
  __shared__ float Xs[16][68];
  __shared__ float Ws[16][68];
  const int tid = threadIdx.x;
  const int tx = tid & 15, ty = tid >> 4;
  const int srow = tid >> 2, skq = (tid & 3) * 4;

  float acc[4][4];
#pragma unroll
  for (int i = 0; i < 4; ++i)
#pragma unroll
    for (int j = 0; j < 4; ++j) acc[i][j] = 0.f;

#pragma unroll 1
  for (int k0 = 0; k0 < HID; k0 += 16) {
    const float4 xv = *(const float4*)&X[(size_t)(t0 + srow) * HID + k0 + skq];
    const float4 wv = *(const float4*)&W[(size_t)(r0 + srow) * HID + k0 + skq];
    __syncthreads();
    Xs[skq + 0][srow] = xv.x; Xs[skq + 1][srow] = xv.y; Xs[skq + 2][srow] = xv.z; Xs[skq + 3][srow] = xv.w;
    Ws[skq + 0][srow] = wv.x; Ws[skq + 1][srow] = wv.y; Ws[skq + 2][srow] = wv.z; Ws[skq + 3][srow] = wv.w;
    __syncthreads();
#pragma unroll
    for (int kk = 0; kk < 16; ++kk) {
      const float4 av = *(const float4*)&Xs[kk][ty * 4];
      const float4 bv = *(const float4*)&Ws[kk][tx * 4];
      acc[0][0] += av.x * bv.x; acc[0][1] += av.x * bv.y; acc[0][2] += av.x * bv.z; acc[0][3] += av.x * bv.w;
      acc[1][0] += av.y * bv.x; acc[1][1] += av.y * bv.y; acc[1][2] += av.y * bv.z; acc[1][3] += av.y * bv.w;
      acc[2][0] += av.z * bv.x; acc[2][1] += av.z * bv.y; acc[2][2] += av.z * bv.z; acc[2][3] += av.z * bv.w;
      acc[3][0] += av.w * bv.x; acc[3][1] += av.w * bv.y; acc[3][2] += av.w * bv.z; acc[3][3] += av.w * bv.w;
    }
  }
  const float* __restrict__ b1 = d ? bihb : bihf;
  const float* __restrict__ b2 = d ? bhhb : bhhf;
  float bias[4];
#pragma unroll
  for (int j = 0; j < 4; ++j) bias[j] = b1[r0 + tx * 4 + j] + b2[r0 + tx * 4 + j];
#pragma unroll
  for (int i = 0; i < 4; ++i) {
    float4 v;
    v.x = acc[i][0] + bias[0]; v.y = acc[i][1] + bias[1];
    v.z = acc[i][2] + bias[2]; v.w = acc[i][3] + bias[3];
    *(float4*)&xg[((size_t)d * T_LEN + t0 + ty * 4 + i) * G4 + r0 + tx * 4] = v;
  }
}

// =========================================================================
// 2) Persistent bidirectional LSTM recurrence — seq-fused single-RT
//    transport (round 3) + one-step-ahead xg prefetch (round 4: keeps the
//    per-step HBM miss latency of the xg stream off the lockstep publish
//    path; the waitcnt for the prefetch lands after the poll loop, ~7000
//    cycles after issue, i.e. free).
// =========================================================================
__global__ __launch_bounds__(256, 1) void lstm_rec(
    const float* __restrict__ xg, const float* __restrict__ whhf,
    const float* __restrict__ whhb, float* __restrict__ hout,
    unsigned long long* __restrict__ hseq)
{
  const int g = blockIdx.x;
  const int d = g >> 7;
  const int s = g & 127;
  const float* __restrict__ whh = d ? whhb : whhf;
  const int tid = threadIdx.x;
  const int sub = tid & 15;   // column group: cols [sub*64, sub*64+64)
  const int rp  = tid >> 4;   // local rows rp and rp+16

  const int lr0 = rp, lr1 = rp + 16;
  const int r0 = ((lr0 >> 3) << 10) + (s << 3) + (lr0 & 7);
  const int r1 = ((lr1 >> 3) << 10) + (s << 3) + (lr1 & 7);

  float w0[64], w1[64];
  {
    const float4* p0 = (const float4*)(whh + (size_t)r0 * HID + sub * 64);
    const float4* p1 = (const float4*)(whh + (size_t)r1 * HID + sub * 64);
#pragma unroll
    for (int b = 0; b < 16; ++b) {
      const float4 v = p0[b];
      w0[4 * b + 0] = v.x; w0[4 * b + 1] = v.y; w0[4 * b + 2] = v.z; w0[4 * b + 3] = v.w;
      const float4 u = p1[b];
      w1[4 * b + 0] = u.x; w1[4 * b + 1] = u.y; w1[4 * b + 2] = u.z; w1[4 * b + 3] = u.w;
    }
  }

  __shared__ float hs[1024];   // swizzled h staging
  __shared__ float gl[32];
  __shared__ int   abortf[1];
  if (tid == 0) abortf[0] = 0;
  float creg = 0.f;            // cell state (used by tid<8 only)
  __syncthreads();

  const float* __restrict__ xgd = xg + (size_t)d * T_LEN * G4;
  // staging slot: element h[G*64+B*4+i] lives at hs[G*64 + ((B+G)&15)*4 + i]
  const int stG = tid >> 4, stB = tid & 15;
  const int stOff = (stG << 6) + ((((stB) + stG) & 15) << 2);

  // xg prefetch ring (depth 1 ahead)
  float xgc0 = 0.f, xgc1 = 0.f;
  if (sub == 0) {
    const int tf = d ? (T_LEN - 1) : 0;
    const float* xr = xgd + (size_t)tf * G4;
    xgc0 = xr[r0]; xgc1 = xr[r1];
  }

#pragma unroll 1
  for (int it = 0; it < T_LEN; ++it) {
    const int t = d ? (T_LEN - 1 - it) : it;
    float xgn0 = 0.f, xgn1 = 0.f;
    if (sub == 0 && it + 1 < T_LEN) {   // issue next step's xg load NOW
      const int tn = d ? (T_LEN - 2 - it) : (it + 1);
      const float* xr = xgd + (size_t)tn * G4;
      xgn0 = xr[r0]; xgn1 = xr[r1];
    }

    if (it > 0) {
      const unsigned long long* hp =
          hseq + ((((size_t)((it - 1) & 1)) * 2 + d) << 10) + (tid << 2);
      const unsigned target = (unsigned)it;  // producers at it-1 stored seq=it
      unsigned long long q0, q1, q2, q3;
      int guard = 1 << 16;
      for (;;) {
        q0 = __hip_atomic_load(hp + 0, __ATOMIC_RELAXED, __HIP_MEMORY_SCOPE_AGENT);
        q1 = __hip_atomic_load(hp + 1, __ATOMIC_RELAXED, __HIP_MEMORY_SCOPE_AGENT);
        q2 = __hip_atomic_load(hp + 2, __ATOMIC_RELAXED, __HIP_MEMORY_SCOPE_AGENT);
        q3 = __hip_atomic_load(hp + 3, __ATOMIC_RELAXED, __HIP_MEMORY_SCOPE_AGENT);
        if ((unsigned)(q0 >> 32) == target && (unsigned)(q1 >> 32) == target &&
            (unsigned)(q2 >> 32) == target && (unsigned)(q3 >> 32) == target) break;
        if (--guard == 0) { abortf[0] = 1; break; }
      }
      float4 hv;
      hv.x = __builtin_bit_cast(float, (unsigned)(q0 & 0xffffffffu));
      hv.y = __builtin_bit_cast(float, (unsigned)(q1 & 0xffffffffu));
      hv.z = __builtin_bit_cast(float, (unsigned)(q2 & 0xffffffffu));
      hv.w = __builtin_bit_cast(float, (unsigned)(q3 & 0xffffffffu));
      *(float4*)&hs[stOff] = hv;
    } else {
      *(float4*)&hs[stOff] = make_float4(0.f, 0.f, 0.f, 0.f);
    }
    __syncthreads();
    if (abortf[0] != 0) break;   // uniform: bail instead of hanging forever

    // reg-resident GEMV: 2 rows x 64 cols per lane, 4 acc chains for ILP
    float a0e = 0.f, a0o = 0.f, a1e = 0.f, a1o = 0.f;
#pragma unroll
    for (int b = 0; b < 16; ++b) {
      const float4 h4 = *(const float4*)&hs[(sub << 6) + (((b + sub) & 15) << 2)];
      if ((b & 1) == 0) {
        a0e += h4.x * w0[4 * b + 0]; a0e += h4.y * w0[4 * b + 1];
        a0e += h4.z * w0[4 * b + 2]; a0e += h4.w * w0[4 * b + 3];
        a1e += h4.x * w1[4 * b + 0]; a1e += h4.y * w1[4 * b + 1];
        a1e += h4.z * w1[4 * b + 2]; a1e += h4.w * w1[4 * b + 3];
      } else {
        a0o += h4.x * w0[4 * b + 0]; a0o += h4.y * w0[4 * b + 1];
        a0o += h4.z * w0[4 * b + 2]; a0o += h4.w * w0[4 * b + 3];
        a1o += h4.x * w1[4 * b + 0]; a1o += h4.y * w1[4 * b + 1];
        a1o += h4.z * w1[4 * b + 2]; a1o += h4.w * w1[4 * b + 3];
      }
    }
    float a0 = a0e + a0o, a1 = a1e + a1o;
#pragma unroll
    for (int m = 1; m < 16; m <<= 1) { a0 += __shfl_xor(a0, m); a1 += __shfl_xor(a1, m); }
    if (sub == 0) { gl[rp] = a0 + xgc0; gl[rp + 16] = a1 + xgc1; }
    __syncthreads();

    if (tid < 8) {
      const float gi = gl[tid], gf = gl[8 + tid], gg = gl[16 + tid], go = gl[24 + tid];
      const float ii = 1.f / (1.f + expf(-gi));
      const float ff = 1.f / (1.f + expf(-gf));
      const float oo = 1.f / (1.f + expf(-go));
      creg = ff * creg + ii * tanhf(gg);
      const float h = oo * tanhf(creg);
      hout[((size_t)d * T_LEN + t) * HID + (s << 3) + tid] = h;  // plain (for dense)
      const unsigned long long pkt =
          ((unsigned long long)(unsigned)(it + 1) << 32) |
          (unsigned long long)__builtin_bit_cast(unsigned, h);
      __hip_atomic_store(hseq + ((((size_t)(it & 1)) * 2 + d) << 10) + (s << 3) + tid,
                         pkt, __ATOMIC_RELAXED, __HIP_MEMORY_SCOPE_AGENT);
    }
    xgc0 = xgn0; xgc1 = xgn1;   // rotate prefetch ring
  }
}

// =========================================================================
// 3) dense_w transpose and feats GEMM
// =========================================================================
__global__ void transpose_w(const float* __restrict__ dw, float* __restrict__ WT) {
  const int i = blockIdx.x * 256 + threadIdx.x;
  if (i < KTAG * 2 * HID) {
    const int k = i / (2 * HID), h = i % (2 * HID);
    WT[(size_t)h * KPAD + k] = dw[i];
  }
}

__global__ __launch_bounds__(256, 2) void dense_kernel(
    const float* __restrict__ hout, const float* __restrict__ WT,
    const float* __restrict__ db, float* __restrict__ feats)
{
  __shared__ float hrow[4][2048];
  const int tid = threadIdx.x, w = tid >> 6, l = tid & 63;
  const int t = blockIdx.x * 4 + w;
  const float* hf = hout + (size_t)t * HID;
  const float* hb = hout + ((size_t)T_LEN + t) * HID;
#pragma unroll
  for (int c = 0; c < 4; ++c)
    *(float4*)&hrow[w][c * 256 + l * 4] = *(const float4*)&hf[c * 256 + l * 4];
#pragma unroll
  for (int c = 0; c < 4; ++c)
    *(float4*)&hrow[w][1024 + c * 256 + l * 4] = *(const float4*)&hb[c * 256 + l * 4];
  __syncthreads();
  float acc = (l < KTAG) ? db[l] : 0.f;
#pragma unroll 4
  for (int h = 0; h < 2 * HID; h += 4) {
    const float4 hv = *(const float4*)&hrow[w][h];
    acc += hv.x * WT[(size_t)(h + 0) * KPAD + l];
    acc += hv.y * WT[(size_t)(h + 1) * KPAD + l];
    acc += hv.z * WT[(size_t)(h + 2) * KPAD + l];
    acc += hv.w * WT[(size_t)(h + 3) * KPAD + l];
  }
  if (l < KTAG) feats[(size_t)t * KPAD + l] = acc;
}

// =========================================================================
// 4) Viterbi forward scan — single wave, fully register-resident.
//    Lane l holds transition row l in 50 VGPRs; fv[p] lives in lane p and
//    is broadcast via v_readlane (SGPR, no LDS, no barriers — one wave is
//    implicitly synced). Argmax = unrolled pairwise (val,idx) tree with
//    strict-> / lower-index-wins => exact numpy first-index semantics.
//    Scores are exactly trans[l][p] + fv[p] (no re-association).
// =========================================================================
__global__ __launch_bounds__(64, 1) void viterbi_fwd(
    const float* __restrict__ feats, const float* __restrict__ trans,
    int* __restrict__ bp, float* __restrict__ out, int* __restrict__ best)
{
  __shared__ float tl[KTAG * 53];
  const int l = threadIdx.x;
  for (int i = l; i < KTAG * KTAG; i += 64) tl[(i / KTAG) * 53 + (i % KTAG)] = trans[i];
  __syncthreads();
  const int lr = (l < KTAG) ? l : (KTAG - 1);
  float tr[KTAG];
#pragma unroll
  for (int p = 0; p < KTAG; ++p) tr[p] = tl[lr * 53 + p];
  const float trE = tl[END_TAG * 53 + lr];

  float fvreg = (l == START_TAG) ? 0.f : -10000.f;
  float ftc = (l < KTAG) ? feats[l] : 0.f;

#pragma unroll 1
  for (int t = 0; t < T_LEN; ++t) {
    float ftn = 0.f;
    if (t + 1 < T_LEN && l < KTAG) ftn = feats[(size_t)(t + 1) * KPAD + l];

    float vm[64]; int va[64];
#pragma unroll
    for (int p = 0; p < KTAG; ++p) {
      const int fb = __builtin_amdgcn_readlane(__builtin_bit_cast(int, fvreg), p);
      vm[p] = tr[p] + __builtin_bit_cast(float, fb);
      va[p] = p;
    }
#pragma unroll
    for (int p = KTAG; p < 64; ++p) { vm[p] = -3.4e38f; va[p] = p; }
#pragma unroll
    for (int w = 32; w >= 1; w >>= 1) {
#pragma unroll
      for (int i = 0; i < w; ++i) {
        if (vm[i + w] > vm[i]) { vm[i] = vm[i + w]; va[i] = va[i + w]; }
      }
    }
    if (l < KTAG) bp[(size_t)t * KPAD + l] = va[0];
    fvreg = vm[0] + ftc;
    ftc = ftn;
  }

  float bv = -3.4e38f; int bi = 1 << 20;
  if (l < KTAG) { bv = fvreg + trE; bi = l; }
#pragma unroll
  for (int m = 1; m < 64; m <<= 1) {
    const float ov = __shfl_xor(bv, m);
    const int   oi = __shfl_xor(bi, m);
    if (ov > bv || (ov == bv && oi < bi)) { bv = ov; bi = oi; }
  }
  if (l == 0) { out[0] = bv; best[0] = bi; }
}

// =========================================================================
// 5) Backtrack via per-chunk map composition (64 chunks of 64 steps)
// =========================================================================
__global__ void bt_chunk(const int* __restrict__ bp, int* __restrict__ mmap) {
  const int c = blockIdx.x, l = threadIdx.x;
  if (l < KTAG) {
    int x = l;
    for (int t = c * 64 + 63; t >= c * 64; --t) x = bp[(size_t)t * KPAD + x];
    mmap[c * 64 + l] = x;
  }
}

__global__ void bt_stitch(const int* __restrict__ mmap, const int* __restrict__ best,
                          int* __restrict__ entry) {
  __shared__ int ml[64 * 64];
  const int tid = threadIdx.x;
  for (int c = 0; c < 64; ++c) ml[c * 64 + tid] = mmap[c * 64 + tid];
  __syncthreads();
  if (tid == 0) {
    int e = best[0];
    for (int c = 63; c >= 0; --c) { entry[c] = e; e = ml[c * 64 + e]; }
  }
}

__global__ void bt_fill(const int* __restrict__ bp, const int* __restrict__ entry,
                        float* __restrict__ out) {
  const int c = blockIdx.x;
  if (threadIdx.x == 0) {
    int x = entry[c];                    // tag at t = c*64+63
    out[1 + c * 64 + 63] = (float)x;
    for (int t = c * 64 + 63; t > c * 64; --t) {
      x = bp[(size_t)t * KPAD + x];
      out[1 + t - 1] = (float)x;
    }
  }
}

// =========================================================================
extern "C" void kernel_launch(void* const* d_in, const int* in_sizes, int n_in,
                              void* d_out, int out_size, void* d_ws, size_t ws_size,
                              hipStream_t stream) {
  (void)in_sizes; (void)n_in; (void)out_size;
  const float* sent  = (const float*)d_in[0];
  const float* wihf  = (const float*)d_in[1];
  const float* whhf  = (const float*)d_in[2];
  const float* bihf  = (const float*)d_in[3];
  const float* bhhf  = (const float*)d_in[4];
  const float* wihb  = (const float*)d_in[5];
  const float* whhb  = (const float*)d_in[6];
  const float* bihb  = (const float*)d_in[7];
  const float* bhhb  = (const float*)d_in[8];
  const float* dw    = (const float*)d_in[9];
  const float* db    = (const float*)d_in[10];
  const float* trans = (const float*)d_in[11];

  if (ws_size < WS_NEEDED) return;
  float* ws    = (float*)d_ws;
  float* xg    = ws + XG_OFF;
  float* hout  = ws + HOUT_OFF;
  float* WT    = ws + WT_OFF;
  float* feats = ws + FEATS_OFF;
  int*   bp    = (int*)(ws + BP_OFF);
  int*   mmap  = (int*)(ws + MMAP_OFF);
  int*   entry = (int*)(ws + ENTRY_OFF);
  int*   best  = (int*)(ws + BEST_OFF);
  unsigned long long* hseq = (unsigned long long*)(ws + HSEQ_OFF);
  float* out = (float*)d_out;

  // zero the 32 KB transport ring: seq targets are >=1, so zeros are inert;
  // keeps every graph replay stale-state-free.
  hipMemsetAsync(hseq, 0, HSEQ_SZ * 4, stream);

  hipLaunchKernelGGL(gemm_xg, dim3(64, 64, 2), dim3(256), 0, stream,
                     sent, wihf, wihb, bihf, bhhf, bihb, bhhb, xg);
  hipLaunchKernelGGL(transpose_w, dim3((KTAG * 2 * HID + 255) / 256), dim3(256), 0, stream,
                     dw, WT);
  {
    const float* a0 = xg; const float* a1 = whhf; const float* a2 = whhb;
    float* a3 = hout; unsigned long long* a4 = hseq;
    void* args[] = { (void*)&a0, (void*)&a1, (void*)&a2, (void*)&a3, (void*)&a4 };
    hipError_t ce = hipLaunchCooperativeKernel((void*)lstm_rec, dim3(256), dim3(256),
                                               args, 0, stream);
    if (ce != hipSuccess) {
      hipLaunchKernelGGL(lstm_rec, dim3(256), dim3(256), 0, stream, a0, a1, a2, a3, a4);
    }
  }
  hipLaunchKernelGGL(dense_kernel, dim3(T_LEN / 4), dim3(256), 0, stream, hout, WT, db, feats);
  hipLaunchKernelGGL(viterbi_fwd, dim3(1), dim3(64), 0, stream, feats, trans, bp, out, best);
  hipLaunchKernelGGL(bt_chunk, dim3(64), dim3(64), 0, stream, bp, mmap);
  hipLaunchKernelGGL(bt_stitch, dim3(1), dim3(64), 0, stream, mmap, best, entry);
  hipLaunchKernelGGL(bt_fill, dim3(64), dim3(64), 0, stream, bp, entry, out);
}

// Round 5
// 15202.682 us; speedup vs baseline: 1.6614x; 1.1458x over previous
//
#include <hip/hip_runtime.h>
#include <math.h>

#define T_LEN 4096
#define HID   1024
#define G4    4096
#define KTAG  50
#define KPAD  64
#define START_TAG 48
#define END_TAG   49

// ---------------- workspace layout (float-element offsets) ----------------
#define XG_OFF     ((size_t)0)                        // [2][T][4096] f32
#define XG_SZ      ((size_t)2*T_LEN*G4)
#define HOUT_OFF   (XG_OFF + XG_SZ)                   // [2][T][1024] f32
#define HOUT_SZ    ((size_t)2*T_LEN*HID)
#define WT_OFF     (HOUT_OFF + HOUT_SZ)               // [2048][64] f32
#define WT_SZ      ((size_t)2*HID*KPAD)
#define FEATS_OFF  (WT_OFF + WT_SZ)                   // [T][64] f32
#define FEATS_SZ   ((size_t)T_LEN*KPAD)
#define BP_OFF     (FEATS_OFF + FEATS_SZ)             // [T][64] i32
#define BP_SZ      ((size_t)T_LEN*KPAD)
#define MMAP_OFF   (BP_OFF + BP_SZ)                   // [64][64] i32
#define MMAP_SZ    ((size_t)64*64)
#define ENTRY_OFF  (MMAP_OFF + MMAP_SZ)               // [64] i32
#define BEST_OFF   (ENTRY_OFF + 64)                   // [1] i32
// seq-fused h transport: [2 slots][2 dirs][1024] u64 (32 KB), 8B-aligned
#define HSEQ_OFF   (((BEST_OFF + 1) + 15) & ~(size_t)15)
#define HSEQ_SZ    ((size_t)8192)                     // in floats (4096 u64)
#define WS_NEEDED  (((HSEQ_OFF + HSEQ_SZ) * 4))

// =========================================================================
// 1) xg[d][t][r] = sum_h X[t][h]*W_ih[d][r][h] + b_ih[r] + b_hh[r]
// =========================================================================
__global__ __launch_bounds__(256, 2) void gemm_xg(
    const float* __restrict__ X, const float* __restrict__ Wf, const float* __restrict__ Wb,
    const float* __restrict__ bihf, const float* __restrict__ bhhf,
    const float* __restrict__ bihb, const float* __restrict__ bhhb,
    float* __restrict__ xg)
{
  const int d  = blockIdx.z;
  const float* __restrict__ W = d ? Wb : Wf;
  const int r0 = blockIdx.x * 64;
  const int t0 = blockIdx.y * 64;
  __shared__ float Xs[16][68];
  __shared__ float Ws[16][68];
  const int tid = threadIdx.x;
  const int tx = tid & 15, ty = tid >> 4;
  const int srow = tid >> 2, skq = (tid & 3) * 4;

  float acc[4][4];
#pragma unroll
  for (int i = 0; i < 4; ++i)
#pragma unroll
    for (int j = 0; j < 4; ++j) acc[i][j] = 0.f;

#pragma unroll 1
  for (int k0 = 0; k0 < HID; k0 += 16) {
    const float4 xv = *(const float4*)&X[(size_t)(t0 + srow) * HID + k0 + skq];
    const float4 wv = *(const float4*)&W[(size_t)(r0 + srow) * HID + k0 + skq];
    __syncthreads();
    Xs[skq + 0][srow] = xv.x; Xs[skq + 1][srow] = xv.y; Xs[skq + 2][srow] = xv.z; Xs[skq + 3][srow] = xv.w;
    Ws[skq + 0][srow] = wv.x; Ws[skq + 1][srow] = wv.y; Ws[skq + 2][srow] = wv.z; Ws[skq + 3][srow] = wv.w;
    __syncthreads();
#pragma unroll
    for (int kk = 0; kk < 16; ++kk) {
      const float4 av = *(const float4*)&Xs[kk][ty * 4];
      const float4 bv = *(const float4*)&Ws[kk][tx * 4];
      acc[0][0] += av.x * bv.x; acc[0][1] += av.x * bv.y; acc[0][2] += av.x * bv.z; acc[0][3] += av.x * bv.w;
      acc[1][0] += av.y * bv.x; acc[1][1] += av.y * bv.y; acc[1][2] += av.y * bv.z; acc[1][3] += av.y * bv.w;
      acc[2][0] += av.z * bv.x; acc[2][1] += av.z * bv.y; acc[2][2] += av.z * bv.z; acc[2][3] += av.z * bv.w;
      acc[3][0] += av.w * bv.x; acc[3][1] += av.w * bv.y; acc[3][2] += av.w * bv.z; acc[3][3] += av.w * bv.w;
    }
  }
  const float* __restrict__ b1 = d ? bihb : bihf;
  const float* __restrict__ b2 = d ? bhhb : bhhf;
  float bias[4];
#pragma unroll
  for (int j = 0; j < 4; ++j) bias[j] = b1[r0 + tx * 4 + j] + b2[r0 + tx * 4 + j];
#pragma unroll
  for (int i = 0; i < 4; ++i) {
    float4 v;
    v.x = acc[i][0] + bias[0]; v.y = acc[i][1] + bias[1];
    v.z = acc[i][2] + bias[2]; v.w = acc[i][3] + bias[3];
    *(float4*)&xg[((size_t)d * T_LEN + t0 + ty * 4 + i) * G4 + r0 + tx * 4] = v;
  }
}

// =========================================================================
// 2) Persistent bidirectional LSTM recurrence.
//    Round 5: 128 WGs x 512 thr (was 256 x 256). WG g: dir d=g>>6,
//    slice s=g&63 owns h[s*16..s*16+16) => 64 gate rows, 128 w-regs/lane.
//    Halves the lockstep participants (straggler tail adds per step) and
//    the per-thread poll fan-in (2 contiguous u64). LDS GEMV reads are
//    bank-rotated ((b+cg)&31) so 8 col-groups hit 8 distinct bank quads.
//    Transport unchanged: u64 {seq, f32} packets, depth-2 ring, AGENT-scope
//    relaxed atomics (single L3 round trip, no fences).
// =========================================================================
__global__ __launch_bounds__(512, 1) void lstm_rec(
    const float* __restrict__ xg, const float* __restrict__ whhf,
    const float* __restrict__ whhb, float* __restrict__ hout,
    unsigned long long* __restrict__ hseq)
{
  const int g = blockIdx.x;
  const int d = g >> 6;
  const int s = g & 63;
  const float* __restrict__ whh = d ? whhb : whhf;
  const int tid = threadIdx.x;
  const int cg  = tid & 7;    // column group: cols [cg*128, cg*128+128)
  const int rid = tid >> 3;   // local gate row 0..63

  // global gate row: gate = rid>>4, within-slice row = rid&15
  const int grow = ((rid >> 4) << 10) + (s << 4) + (rid & 15);

  // 128 weight regs/lane, stored in bank-rotated block order:
  // w[4b+i] pairs with h[cg*128 + ((b+cg)&31)*4 + i]
  float w[128];
  {
    const float* wr = whh + (size_t)grow * HID + (cg << 7);
#pragma unroll
    for (int b = 0; b < 32; ++b) {
      const int bb = (b + cg) & 31;
      const float4 v = *(const float4*)&wr[bb << 2];
      w[4 * b + 0] = v.x; w[4 * b + 1] = v.y; w[4 * b + 2] = v.z; w[4 * b + 3] = v.w;
    }
  }

  __shared__ float hs[1024];   // linear h staging
  __shared__ float gl[64];     // gate sums
  __shared__ int   abortf[1];
  if (tid == 0) abortf[0] = 0;
  float creg = 0.f;            // cell state (lanes tid<16 of wave 0)
  __syncthreads();

  const float* __restrict__ xgd = xg + (size_t)d * T_LEN * G4;

  // xg prefetch (depth 1 ahead), cg==0 lanes only
  float xgc = 0.f;
  if (cg == 0) {
    const int tf = d ? (T_LEN - 1) : 0;
    xgc = xgd[(size_t)tf * G4 + grow];
  }

#pragma unroll 1
  for (int it = 0; it < T_LEN; ++it) {
    const int t = d ? (T_LEN - 1 - it) : it;
    float xgn = 0.f;
    if (cg == 0 && it + 1 < T_LEN) {
      const int tn = d ? (T_LEN - 2 - it) : (it + 1);
      xgn = xgd[(size_t)tn * G4 + grow];
    }

    if (it > 0) {
      const unsigned long long* hp =
          hseq + ((((size_t)((it - 1) & 1)) * 2 + d) << 10) + (tid << 1);
      const unsigned target = (unsigned)it;  // producers at it-1 stored seq=it
      unsigned long long q0, q1;
      int guard = 1 << 17;
      for (;;) {
        q0 = __hip_atomic_load(hp + 0, __ATOMIC_RELAXED, __HIP_MEMORY_SCOPE_AGENT);
        q1 = __hip_atomic_load(hp + 1, __ATOMIC_RELAXED, __HIP_MEMORY_SCOPE_AGENT);
        if ((unsigned)(q0 >> 32) == target && (unsigned)(q1 >> 32) == target) break;
        if (--guard == 0) { abortf[0] = 1; break; }
      }
      float2 hv;
      hv.x = __builtin_bit_cast(float, (unsigned)(q0 & 0xffffffffu));
      hv.y = __builtin_bit_cast(float, (unsigned)(q1 & 0xffffffffu));
      *(float2*)&hs[tid << 1] = hv;
    } else {
      *(float2*)&hs[tid << 1] = make_float2(0.f, 0.f);
    }
    __syncthreads();
    if (abortf[0] != 0) break;   // uniform: bail instead of hanging forever

    // reg-resident GEMV: 1 row x 128 cols per lane, 2 acc chains,
    // bank-rotated reads (conflict-free across the 8 cgs of a wave)
    float aE = 0.f, aO = 0.f;
    const int hbase = cg << 7;
#pragma unroll
    for (int b = 0; b < 32; ++b) {
      const int bb = (b + cg) & 31;
      const float4 h4 = *(const float4*)&hs[hbase + (bb << 2)];
      if ((b & 1) == 0) {
        aE += h4.x * w[4 * b + 0]; aE += h4.y * w[4 * b + 1];
        aE += h4.z * w[4 * b + 2]; aE += h4.w * w[4 * b + 3];
      } else {
        aO += h4.x * w[4 * b + 0]; aO += h4.y * w[4 * b + 1];
        aO += h4.z * w[4 * b + 2]; aO += h4.w * w[4 * b + 3];
      }
    }
    float a = aE + aO;
#pragma unroll
    for (int m = 1; m < 8; m <<= 1) a += __shfl_xor(a, m);
    if (cg == 0) gl[rid] = a + xgc;
    __syncthreads();

    if (tid < 16) {
      const float gi = gl[tid], gf = gl[16 + tid], gg = gl[32 + tid], go = gl[48 + tid];
      const float ii = 1.f / (1.f + expf(-gi));
      const float ff = 1.f / (1.f + expf(-gf));
      const float oo = 1.f / (1.f + expf(-go));
      creg = ff * creg + ii * tanhf(gg);
      const float h = oo * tanhf(creg);
      hout[((size_t)d * T_LEN + t) * HID + (s << 4) + tid] = h;  // plain (for dense)
      const unsigned long long pkt =
          ((unsigned long long)(unsigned)(it + 1) << 32) |
          (unsigned long long)__builtin_bit_cast(unsigned, h);
      __hip_atomic_store(hseq + ((((size_t)(it & 1)) * 2 + d) << 10) + (s << 4) + tid,
                         pkt, __ATOMIC_RELAXED, __HIP_MEMORY_SCOPE_AGENT);
    }
    xgc = xgn;   // rotate prefetch ring
  }
}

// =========================================================================
// 3) dense_w transpose and feats GEMM
// =========================================================================
__global__ void transpose_w(const float* __restrict__ dw, float* __restrict__ WT) {
  const int i = blockIdx.x * 256 + threadIdx.x;
  if (i < KTAG * 2 * HID) {
    const int k = i / (2 * HID), h = i % (2 * HID);
    WT[(size_t)h * KPAD + k] = dw[i];
  }
}

__global__ __launch_bounds__(256, 2) void dense_kernel(
    const float* __restrict__ hout, const float* __restrict__ WT,
    const float* __restrict__ db, float* __restrict__ feats)
{
  __shared__ float hrow[4][2048];
  const int tid = threadIdx.x, w = tid >> 6, l = tid & 63;
  const int t = blockIdx.x * 4 + w;
  const float* hf = hout + (size_t)t * HID;
  const float* hb = hout + ((size_t)T_LEN + t) * HID;
#pragma unroll
  for (int c = 0; c < 4; ++c)
    *(float4*)&hrow[w][c * 256 + l * 4] = *(const float4*)&hf[c * 256 + l * 4];
#pragma unroll
  for (int c = 0; c < 4; ++c)
    *(float4*)&hrow[w][1024 + c * 256 + l * 4] = *(const float4*)&hb[c * 256 + l * 4];
  __syncthreads();
  float acc = (l < KTAG) ? db[l] : 0.f;
#pragma unroll 4
  for (int h = 0; h < 2 * HID; h += 4) {
    const float4 hv = *(const float4*)&hrow[w][h];
    acc += hv.x * WT[(size_t)(h + 0) * KPAD + l];
    acc += hv.y * WT[(size_t)(h + 1) * KPAD + l];
    acc += hv.z * WT[(size_t)(h + 2) * KPAD + l];
    acc += hv.w * WT[(size_t)(h + 3) * KPAD + l];
  }
  if (l < KTAG) feats[(size_t)t * KPAD + l] = acc;
}

// =========================================================================
// 4) Viterbi forward scan — single wave, fully register-resident.
// =========================================================================
__global__ __launch_bounds__(64, 1) void viterbi_fwd(
    const float* __restrict__ feats, const float* __restrict__ trans,
    int* __restrict__ bp, float* __restrict__ out, int* __restrict__ best)
{
  __shared__ float tl[KTAG * 53];
  const int l = threadIdx.x;
  for (int i = l; i < KTAG * KTAG; i += 64) tl[(i / KTAG) * 53 + (i % KTAG)] = trans[i];
  __syncthreads();
  const int lr = (l < KTAG) ? l : (KTAG - 1);
  float tr[KTAG];
#pragma unroll
  for (int p = 0; p < KTAG; ++p) tr[p] = tl[lr * 53 + p];
  const float trE = tl[END_TAG * 53 + lr];

  float fvreg = (l == START_TAG) ? 0.f : -10000.f;
  float ftc = (l < KTAG) ? feats[l] : 0.f;

#pragma unroll 1
  for (int t = 0; t < T_LEN; ++t) {
    float ftn = 0.f;
    if (t + 1 < T_LEN && l < KTAG) ftn = feats[(size_t)(t + 1) * KPAD + l];

    float vm[64]; int va[64];
#pragma unroll
    for (int p = 0; p < KTAG; ++p) {
      const int fb = __builtin_amdgcn_readlane(__builtin_bit_cast(int, fvreg), p);
      vm[p] = tr[p] + __builtin_bit_cast(float, fb);
      va[p] = p;
    }
#pragma unroll
    for (int p = KTAG; p < 64; ++p) { vm[p] = -3.4e38f; va[p] = p; }
#pragma unroll
    for (int w = 32; w >= 1; w >>= 1) {
#pragma unroll
      for (int i = 0; i < w; ++i) {
        if (vm[i + w] > vm[i]) { vm[i] = vm[i + w]; va[i] = va[i + w]; }
      }
    }
    if (l < KTAG) bp[(size_t)t * KPAD + l] = va[0];
    fvreg = vm[0] + ftc;
    ftc = ftn;
  }

  float bv = -3.4e38f; int bi = 1 << 20;
  if (l < KTAG) { bv = fvreg + trE; bi = l; }
#pragma unroll
  for (int m = 1; m < 64; m <<= 1) {
    const float ov = __shfl_xor(bv, m);
    const int   oi = __shfl_xor(bi, m);
    if (ov > bv || (ov == bv && oi < bi)) { bv = ov; bi = oi; }
  }
  if (l == 0) { out[0] = bv; best[0] = bi; }
}

// =========================================================================
// 5) Backtrack via per-chunk map composition (64 chunks of 64 steps)
// =========================================================================
__global__ void bt_chunk(const int* __restrict__ bp, int* __restrict__ mmap) {
  const int c = blockIdx.x, l = threadIdx.x;
  if (l < KTAG) {
    int x = l;
    for (int t = c * 64 + 63; t >= c * 64; --t) x = bp[(size_t)t * KPAD + x];
    mmap[c * 64 + l] = x;
  }
}

__global__ void bt_stitch(const int* __restrict__ mmap, const int* __restrict__ best,
                          int* __restrict__ entry) {
  __shared__ int ml[64 * 64];
  const int tid = threadIdx.x;
  for (int c = 0; c < 64; ++c) ml[c * 64 + tid] = mmap[c * 64 + tid];
  __syncthreads();
  if (tid == 0) {
    int e = best[0];
    for (int c = 63; c >= 0; --c) { entry[c] = e; e = ml[c * 64 + e]; }
  }
}

__global__ void bt_fill(const int* __restrict__ bp, const int* __restrict__ entry,
                        float* __restrict__ out) {
  const int c = blockIdx.x;
  if (threadIdx.x == 0) {
    int x = entry[c];                    // tag at t = c*64+63
    out[1 + c * 64 + 63] = (float)x;
    for (int t = c * 64 + 63; t > c * 64; --t) {
      x = bp[(size_t)t * KPAD + x];
      out[1 + t - 1] = (float)x;
    }
  }
}

// =========================================================================
extern "C" void kernel_launch(void* const* d_in, const int* in_sizes, int n_in,
                              void* d_out, int out_size, void* d_ws, size_t ws_size,
                              hipStream_t stream) {
  (void)in_sizes; (void)n_in; (void)out_size;
  const float* sent  = (const float*)d_in[0];
  const float* wihf  = (const float*)d_in[1];
  const float* whhf  = (const float*)d_in[2];
  const float* bihf  = (const float*)d_in[3];
  const float* bhhf  = (const float*)d_in[4];
  const float* wihb  = (const float*)d_in[5];
  const float* whhb  = (const float*)d_in[6];
  const float* bihb  = (const float*)d_in[7];
  const float* bhhb  = (const float*)d_in[8];
  const float* dw    = (const float*)d_in[9];
  const float* db    = (const float*)d_in[10];
  const float* trans = (const float*)d_in[11];

  if (ws_size < WS_NEEDED) return;
  float* ws    = (float*)d_ws;
  float* xg    = ws + XG_OFF;
  float* hout  = ws + HOUT_OFF;
  float* WT    = ws + WT_OFF;
  float* feats = ws + FEATS_OFF;
  int*   bp    = (int*)(ws + BP_OFF);
  int*   mmap  = (int*)(ws + MMAP_OFF);
  int*   entry = (int*)(ws + ENTRY_OFF);
  int*   best  = (int*)(ws + BEST_OFF);
  unsigned long long* hseq = (unsigned long long*)(ws + HSEQ_OFF);
  float* out = (float*)d_out;

  // zero the 32 KB transport ring: seq targets are >=1, so zeros are inert;
  // keeps every graph replay stale-state-free.
  hipMemsetAsync(hseq, 0, HSEQ_SZ * 4, stream);

  hipLaunchKernelGGL(gemm_xg, dim3(64, 64, 2), dim3(256), 0, stream,
                     sent, wihf, wihb, bihf, bhhf, bihb, bhhb, xg);
  hipLaunchKernelGGL(transpose_w, dim3((KTAG * 2 * HID + 255) / 256), dim3(256), 0, stream,
                     dw, WT);
  {
    const float* a0 = xg; const float* a1 = whhf; const float* a2 = whhb;
    float* a3 = hout; unsigned long long* a4 = hseq;
    void* args[] = { (void*)&a0, (void*)&a1, (void*)&a2, (void*)&a3, (void*)&a4 };
    hipError_t ce = hipLaunchCooperativeKernel((void*)lstm_rec, dim3(128), dim3(512),
                                               args, 0, stream);
    if (ce != hipSuccess) {
      hipLaunchKernelGGL(lstm_rec, dim3(128), dim3(512), 0, stream, a0, a1, a2, a3, a4);
    }
  }
  hipLaunchKernelGGL(dense_kernel, dim3(T_LEN / 4), dim3(256), 0, stream, hout, WT, db, feats);
  hipLaunchKernelGGL(viterbi_fwd, dim3(1), dim3(64), 0, stream, feats, trans, bp, out, best);
  hipLaunchKernelGGL(bt_chunk, dim3(64), dim3(64), 0, stream, bp, mmap);
  hipLaunchKernelGGL(bt_stitch, dim3(1), dim3(64), 0, stream, mmap, best, entry);
  hipLaunchKernelGGL(bt_fill, dim3(64), dim3(64), 0, stream, bp, entry, out);
}

// Round 6
// 13798.547 us; speedup vs baseline: 1.8304x; 1.1018x over previous
//
#include <hip/hip_runtime.h>
#include <math.h>

#define T_LEN 4096
#define HID   1024
#define G4    4096
#define KTAG  50
#define KPAD  64
#define START_TAG 48
#define END_TAG   49

// ---------------- workspace layout (float-element offsets) ----------------
#define XG_OFF     ((size_t)0)                        // [2][T][4096] f32
#define XG_SZ      ((size_t)2*T_LEN*G4)
#define HOUT_OFF   (XG_OFF + XG_SZ)                   // [2][T][1024] f32
#define HOUT_SZ    ((size_t)2*T_LEN*HID)
#define WT_OFF     (HOUT_OFF + HOUT_SZ)               // [2048][64] f32
#define WT_SZ      ((size_t)2*HID*KPAD)
#define FEATS_OFF  (WT_OFF + WT_SZ)                   // [T][64] f32
#define FEATS_SZ   ((size_t)T_LEN*KPAD)
#define BP_OFF     (FEATS_OFF + FEATS_SZ)             // [T][64] i32
#define BP_SZ      ((size_t)T_LEN*KPAD)
#define MMAP_OFF   (BP_OFF + BP_SZ)                   // [64][64] i32
#define MMAP_SZ    ((size_t)64*64)
#define ENTRY_OFF  (MMAP_OFF + MMAP_SZ)               // [64] i32
#define BEST_OFF   (ENTRY_OFF + 64)                   // [1] i32
// seq-fused h transport: [2 slots][2 dirs][1024] u64 (32 KB), 8B-aligned
#define HSEQ_OFF   (((BEST_OFF + 1) + 15) & ~(size_t)15)
#define HSEQ_SZ    ((size_t)8192)                     // in floats (4096 u64)
#define WS_NEEDED  (((HSEQ_OFF + HSEQ_SZ) * 4))

// =========================================================================
// 1) xg[d][t][r] = sum_h X[t][h]*W_ih[d][r][h] + b_ih[r] + b_hh[r]
// =========================================================================
__global__ __launch_bounds__(256, 2) void gemm_xg(
    const float* __restrict__ X, const float* __restrict__ Wf, const float* __restrict__ Wb,
    const float* __restrict__ bihf, const float* __restrict__ bhhf,
    const float* __restrict__ bihb, const float* __restrict__ bhhb,
    float* __restrict__ xg)
{
  const int d  = blockIdx.z;
  const float* __restrict__ W = d ? Wb : Wf;
  const int r0 = blockIdx.x * 64;
  const int t0 = blockIdx.y * 64;
  __shared__ float Xs[16][68];
  __shared__ float Ws[16][68];
  const int tid = threadIdx.x;
  const int tx = tid & 15, ty = tid >> 4;
  const int srow = tid >> 2, skq = (tid & 3) * 4;

  float acc[4][4];
#pragma unroll
  for (int i = 0; i < 4; ++i)
#pragma unroll
    for (int j = 0; j < 4; ++j) acc[i][j] = 0.f;

#pragma unroll 1
  for (int k0 = 0; k0 < HID; k0 += 16) {
    const float4 xv = *(const float4*)&X[(size_t)(t0 + srow) * HID + k0 + skq];
    const float4 wv = *(const float4*)&W[(size_t)(r0 + srow) * HID + k0 + skq];
    __syncthreads();
    Xs[skq + 0][srow] = xv.x; Xs[skq + 1][srow] = xv.y; Xs[skq + 2][srow] = xv.z; Xs[skq + 3][srow] = xv.w;
    Ws[skq + 0][srow] = wv.x; Ws[skq + 1][srow] = wv.y; Ws[skq + 2][srow] = wv.z; Ws[skq + 3][srow] = wv.w;
    __syncthreads();
#pragma unroll
    for (int kk = 0; kk < 16; ++kk) {
      const float4 av = *(const float4*)&Xs[kk][ty * 4];
      const float4 bv = *(const float4*)&Ws[kk][tx * 4];
      acc[0][0] += av.x * bv.x; acc[0][1] += av.x * bv.y; acc[0][2] += av.x * bv.z; acc[0][3] += av.x * bv.w;
      acc[1][0] += av.y * bv.x; acc[1][1] += av.y * bv.y; acc[1][2] += av.y * bv.z; acc[1][3] += av.y * bv.w;
      acc[2][0] += av.z * bv.x; acc[2][1] += av.z * bv.y; acc[2][2] += av.z * bv.z; acc[2][3] += av.z * bv.w;
      acc[3][0] += av.w * bv.x; acc[3][1] += av.w * bv.y; acc[3][2] += av.w * bv.z; acc[3][3] += av.w * bv.w;
    }
  }
  const float* __restrict__ b1 = d ? bihb : bihf;
  const float* __restrict__ b2 = d ? bhhb : bhhf;
  float bias[4];
#pragma unroll
  for (int j = 0; j < 4; ++j) bias[j] = b1[r0 + tx * 4 + j] + b2[r0 + tx * 4 + j];
#pragma unroll
  for (int i = 0; i < 4; ++i) {
    float4 v;
    v.x = acc[i][0] + bias[0]; v.y = acc[i][1] + bias[1];
    v.z = acc[i][2] + bias[2]; v.w = acc[i][3] + bias[3];
    *(float4*)&xg[((size_t)d * T_LEN + t0 + ty * 4 + i) * G4 + r0 + tx * 4] = v;
  }
}

// =========================================================================
// 2) Persistent bidirectional LSTM recurrence.
//    Round 6: gate-blocked GEMV. 128 WGs x 512 thr; 32-lane group owns ONE
//    h output; lane = 4 gate rows x 32 cols (128 w-regs, 128 FMA — same
//    compute, but only 32 h-floats read per lane per step: 4x less LDS
//    traffic than round 5, which was ~half the step time). After the
//    32-lane butterfly reduce the group leader holds all 4 gate sums ->
//    activations + publish fully in-register: NO gl staging, ONE barrier
//    per step (hs is double-buffered to make that legal).
//    Transport unchanged: u64 {seq, f32} packets, depth-2 ring, AGENT-scope
//    relaxed atomics (single L3 round trip, no fences).
// =========================================================================
__global__ __launch_bounds__(512, 1) void lstm_rec(
    const float* __restrict__ xg, const float* __restrict__ whhf,
    const float* __restrict__ whhb, float* __restrict__ hout,
    unsigned long long* __restrict__ hseq)
{
  const int g = blockIdx.x;
  const int d = g >> 6;
  const int s = g & 63;
  const float* __restrict__ whh = d ? whhb : whhf;
  const int tid = threadIdx.x;
  const int ln   = tid & 31;    // lane within h-group
  const int gidx = tid >> 5;    // h-slot 0..15 within slice
  const int hidx = (s << 4) + gidx;   // global h index 0..1023

  // 128 weight regs: 4 gates x 32 cols. Block k pairs with
  // h[ln*32 + ((k+ln)&7)*4 + i] (lane-rotated -> banks evenly spread;
  // upper 32 lanes read identical addresses -> LDS broadcast, free).
  float w[4][32];
#pragma unroll
  for (int gt = 0; gt < 4; ++gt) {
    const float* wr = whh + ((size_t)(gt << 10) + hidx) * HID + (ln << 5);
#pragma unroll
    for (int k = 0; k < 8; ++k) {
      const int bb = (k + ln) & 7;
      const float4 v = *(const float4*)&wr[bb << 2];
      w[gt][4 * k + 0] = v.x; w[gt][4 * k + 1] = v.y;
      w[gt][4 * k + 2] = v.z; w[gt][4 * k + 3] = v.w;
    }
  }

  __shared__ float hs[2][1024];   // double-buffered h staging
  __shared__ int   abortf[1];
  if (tid == 0) abortf[0] = 0;
  float creg = 0.f;               // cell state (group leaders only)
  __syncthreads();

  const float* __restrict__ xgd = xg + (size_t)d * T_LEN * G4;

  // xg prefetch (depth 1 ahead), leaders only: 4 gate terms for this h
  float xc0 = 0.f, xc1 = 0.f, xc2 = 0.f, xc3 = 0.f;
  if (ln == 0) {
    const int tf = d ? (T_LEN - 1) : 0;
    const float* xr = xgd + (size_t)tf * G4 + hidx;
    xc0 = xr[0]; xc1 = xr[HID]; xc2 = xr[2 * HID]; xc3 = xr[3 * HID];
  }

#pragma unroll 1
  for (int it = 0; it < T_LEN; ++it) {
    const int t = d ? (T_LEN - 1 - it) : it;
    float xn0 = 0.f, xn1 = 0.f, xn2 = 0.f, xn3 = 0.f;
    if (ln == 0 && it + 1 < T_LEN) {   // issue next step's xg loads NOW
      const int tn = d ? (T_LEN - 2 - it) : (it + 1);
      const float* xr = xgd + (size_t)tn * G4 + hidx;
      xn0 = xr[0]; xn1 = xr[HID]; xn2 = xr[2 * HID]; xn3 = xr[3 * HID];
    }

    const int buf = it & 1;
    if (it > 0) {
      const unsigned long long* hp =
          hseq + ((((size_t)((it - 1) & 1)) * 2 + d) << 10) + (tid << 1);
      const unsigned target = (unsigned)it;  // producers at it-1 stored seq=it
      unsigned long long q0, q1;
      int guard = 1 << 17;
      for (;;) {
        q0 = __hip_atomic_load(hp + 0, __ATOMIC_RELAXED, __HIP_MEMORY_SCOPE_AGENT);
        q1 = __hip_atomic_load(hp + 1, __ATOMIC_RELAXED, __HIP_MEMORY_SCOPE_AGENT);
        if ((unsigned)(q0 >> 32) == target && (unsigned)(q1 >> 32) == target) break;
        if (--guard == 0) { abortf[0] = 1; break; }
      }
      float2 hv;
      hv.x = __builtin_bit_cast(float, (unsigned)(q0 & 0xffffffffu));
      hv.y = __builtin_bit_cast(float, (unsigned)(q1 & 0xffffffffu));
      *(float2*)&hs[buf][tid << 1] = hv;
    } else {
      *(float2*)&hs[buf][tid << 1] = make_float2(0.f, 0.f);
    }
    __syncthreads();                     // the ONLY barrier per step
    if (abortf[0] != 0) break;           // uniform bail (no deadlock)

    // gate-blocked GEMV: 8 x ds_read_b128, each reused by 4 gates
    float a0 = 0.f, a1 = 0.f, a2 = 0.f, a3 = 0.f;
    const float* hb = &hs[buf][ln << 5];
#pragma unroll
    for (int k = 0; k < 8; ++k) {
      const int bb = (k + ln) & 7;
      const float4 h4 = *(const float4*)&hb[bb << 2];
      a0 += h4.x * w[0][4 * k + 0]; a0 += h4.y * w[0][4 * k + 1];
      a0 += h4.z * w[0][4 * k + 2]; a0 += h4.w * w[0][4 * k + 3];
      a1 += h4.x * w[1][4 * k + 0]; a1 += h4.y * w[1][4 * k + 1];
      a1 += h4.z * w[1][4 * k + 2]; a1 += h4.w * w[1][4 * k + 3];
      a2 += h4.x * w[2][4 * k + 0]; a2 += h4.y * w[2][4 * k + 1];
      a2 += h4.z * w[2][4 * k + 2]; a2 += h4.w * w[2][4 * k + 3];
      a3 += h4.x * w[3][4 * k + 0]; a3 += h4.y * w[3][4 * k + 1];
      a3 += h4.z * w[3][4 * k + 2]; a3 += h4.w * w[3][4 * k + 3];
    }
    // 32-lane butterfly (xor masks 1..16 stay within each 32-lane group)
#pragma unroll
    for (int m = 1; m < 32; m <<= 1) {
      a0 += __shfl_xor(a0, m); a1 += __shfl_xor(a1, m);
      a2 += __shfl_xor(a2, m); a3 += __shfl_xor(a3, m);
    }

    if (ln == 0) {   // leader: all 4 gate sums in-register
      const float gi = a0 + xc0, gf = a1 + xc1, gg = a2 + xc2, go = a3 + xc3;
      const float ii = 1.f / (1.f + expf(-gi));
      const float ff = 1.f / (1.f + expf(-gf));
      const float oo = 1.f / (1.f + expf(-go));
      creg = ff * creg + ii * tanhf(gg);
      const float h = oo * tanhf(creg);
      hout[((size_t)d * T_LEN + t) * HID + hidx] = h;  // plain (for dense)
      const unsigned long long pkt =
          ((unsigned long long)(unsigned)(it + 1) << 32) |
          (unsigned long long)__builtin_bit_cast(unsigned, h);
      __hip_atomic_store(hseq + ((((size_t)(it & 1)) * 2 + d) << 10) + hidx,
                         pkt, __ATOMIC_RELAXED, __HIP_MEMORY_SCOPE_AGENT);
    }
    xc0 = xn0; xc1 = xn1; xc2 = xn2; xc3 = xn3;   // rotate prefetch
  }
}

// =========================================================================
// 3) dense_w transpose and feats GEMM
// =========================================================================
__global__ void transpose_w(const float* __restrict__ dw, float* __restrict__ WT) {
  const int i = blockIdx.x * 256 + threadIdx.x;
  if (i < KTAG * 2 * HID) {
    const int k = i / (2 * HID), h = i % (2 * HID);
    WT[(size_t)h * KPAD + k] = dw[i];
  }
}

__global__ __launch_bounds__(256, 2) void dense_kernel(
    const float* __restrict__ hout, const float* __restrict__ WT,
    const float* __restrict__ db, float* __restrict__ feats)
{
  __shared__ float hrow[4][2048];
  const int tid = threadIdx.x, w = tid >> 6, l = tid & 63;
  const int t = blockIdx.x * 4 + w;
  const float* hf = hout + (size_t)t * HID;
  const float* hb = hout + ((size_t)T_LEN + t) * HID;
#pragma unroll
  for (int c = 0; c < 4; ++c)
    *(float4*)&hrow[w][c * 256 + l * 4] = *(const float4*)&hf[c * 256 + l * 4];
#pragma unroll
  for (int c = 0; c < 4; ++c)
    *(float4*)&hrow[w][1024 + c * 256 + l * 4] = *(const float4*)&hb[c * 256 + l * 4];
  __syncthreads();
  float acc = (l < KTAG) ? db[l] : 0.f;
#pragma unroll 4
  for (int h = 0; h < 2 * HID; h += 4) {
    const float4 hv = *(const float4*)&hrow[w][h];
    acc += hv.x * WT[(size_t)(h + 0) * KPAD + l];
    acc += hv.y * WT[(size_t)(h + 1) * KPAD + l];
    acc += hv.z * WT[(size_t)(h + 2) * KPAD + l];
    acc += hv.w * WT[(size_t)(h + 3) * KPAD + l];
  }
  if (l < KTAG) feats[(size_t)t * KPAD + l] = acc;
}

// =========================================================================
// 4) Viterbi forward scan — single wave, fully register-resident.
// =========================================================================
__global__ __launch_bounds__(64, 1) void viterbi_fwd(
    const float* __restrict__ feats, const float* __restrict__ trans,
    int* __restrict__ bp, float* __restrict__ out, int* __restrict__ best)
{
  __shared__ float tl[KTAG * 53];
  const int l = threadIdx.x;
  for (int i = l; i < KTAG * KTAG; i += 64) tl[(i / KTAG) * 53 + (i % KTAG)] = trans[i];
  __syncthreads();
  const int lr = (l < KTAG) ? l : (KTAG - 1);
  float tr[KTAG];
#pragma unroll
  for (int p = 0; p < KTAG; ++p) tr[p] = tl[lr * 53 + p];
  const float trE = tl[END_TAG * 53 + lr];

  float fvreg = (l == START_TAG) ? 0.f : -10000.f;
  float ftc = (l < KTAG) ? feats[l] : 0.f;

#pragma unroll 1
  for (int t = 0; t < T_LEN; ++t) {
    float ftn = 0.f;
    if (t + 1 < T_LEN && l < KTAG) ftn = feats[(size_t)(t + 1) * KPAD + l];

    float vm[64]; int va[64];
#pragma unroll
    for (int p = 0; p < KTAG; ++p) {
      const int fb = __builtin_amdgcn_readlane(__builtin_bit_cast(int, fvreg), p);
      vm[p] = tr[p] + __builtin_bit_cast(float, fb);
      va[p] = p;
    }
#pragma unroll
    for (int p = KTAG; p < 64; ++p) { vm[p] = -3.4e38f; va[p] = p; }
#pragma unroll
    for (int w = 32; w >= 1; w >>= 1) {
#pragma unroll
      for (int i = 0; i < w; ++i) {
        if (vm[i + w] > vm[i]) { vm[i] = vm[i + w]; va[i] = va[i + w]; }
      }
    }
    if (l < KTAG) bp[(size_t)t * KPAD + l] = va[0];
    fvreg = vm[0] + ftc;
    ftc = ftn;
  }

  float bv = -3.4e38f; int bi = 1 << 20;
  if (l < KTAG) { bv = fvreg + trE; bi = l; }
#pragma unroll
  for (int m = 1; m < 64; m <<= 1) {
    const float ov = __shfl_xor(bv, m);
    const int   oi = __shfl_xor(bi, m);
    if (ov > bv || (ov == bv && oi < bi)) { bv = ov; bi = oi; }
  }
  if (l == 0) { out[0] = bv; best[0] = bi; }
}

// =========================================================================
// 5) Backtrack via per-chunk map composition (64 chunks of 64 steps)
// =========================================================================
__global__ void bt_chunk(const int* __restrict__ bp, int* __restrict__ mmap) {
  const int c = blockIdx.x, l = threadIdx.x;
  if (l < KTAG) {
    int x = l;
    for (int t = c * 64 + 63; t >= c * 64; --t) x = bp[(size_t)t * KPAD + x];
    mmap[c * 64 + l] = x;
  }
}

__global__ void bt_stitch(const int* __restrict__ mmap, const int* __restrict__ best,
                          int* __restrict__ entry) {
  __shared__ int ml[64 * 64];
  const int tid = threadIdx.x;
  for (int c = 0; c < 64; ++c) ml[c * 64 + tid] = mmap[c * 64 + tid];
  __syncthreads();
  if (tid == 0) {
    int e = best[0];
    for (int c = 63; c >= 0; --c) { entry[c] = e; e = ml[c * 64 + e]; }
  }
}

__global__ void bt_fill(const int* __restrict__ bp, const int* __restrict__ entry,
                        float* __restrict__ out) {
  const int c = blockIdx.x;
  if (threadIdx.x == 0) {
    int x = entry[c];                    // tag at t = c*64+63
    out[1 + c * 64 + 63] = (float)x;
    for (int t = c * 64 + 63; t > c * 64; --t) {
      x = bp[(size_t)t * KPAD + x];
      out[1 + t - 1] = (float)x;
    }
  }
}

// =========================================================================
extern "C" void kernel_launch(void* const* d_in, const int* in_sizes, int n_in,
                              void* d_out, int out_size, void* d_ws, size_t ws_size,
                              hipStream_t stream) {
  (void)in_sizes; (void)n_in; (void)out_size;
  const float* sent  = (const float*)d_in[0];
  const float* wihf  = (const float*)d_in[1];
  const float* whhf  = (const float*)d_in[2];
  const float* bihf  = (const float*)d_in[3];
  const float* bhhf  = (const float*)d_in[4];
  const float* wihb  = (const float*)d_in[5];
  const float* whhb  = (const float*)d_in[6];
  const float* bihb  = (const float*)d_in[7];
  const float* bhhb  = (const float*)d_in[8];
  const float* dw    = (const float*)d_in[9];
  const float* db    = (const float*)d_in[10];
  const float* trans = (const float*)d_in[11];

  if (ws_size < WS_NEEDED) return;
  float* ws    = (float*)d_ws;
  float* xg    = ws + XG_OFF;
  float* hout  = ws + HOUT_OFF;
  float* WT    = ws + WT_OFF;
  float* feats = ws + FEATS_OFF;
  int*   bp    = (int*)(ws + BP_OFF);
  int*   mmap  = (int*)(ws + MMAP_OFF);
  int*   entry = (int*)(ws + ENTRY_OFF);
  int*   best  = (int*)(ws + BEST_OFF);
  unsigned long long* hseq = (unsigned long long*)(ws + HSEQ_OFF);
  float* out = (float*)d_out;

  // zero the 32 KB transport ring: seq targets are >=1, so zeros are inert;
  // keeps every graph replay stale-state-free.
  hipMemsetAsync(hseq, 0, HSEQ_SZ * 4, stream);

  hipLaunchKernelGGL(gemm_xg, dim3(64, 64, 2), dim3(256), 0, stream,
                     sent, wihf, wihb, bihf, bhhf, bihb, bhhb, xg);
  hipLaunchKernelGGL(transpose_w, dim3((KTAG * 2 * HID + 255) / 256), dim3(256), 0, stream,
                     dw, WT);
  {
    const float* a0 = xg; const float* a1 = whhf; const float* a2 = whhb;
    float* a3 = hout; unsigned long long* a4 = hseq;
    void* args[] = { (void*)&a0, (void*)&a1, (void*)&a2, (void*)&a3, (void*)&a4 };
    hipError_t ce = hipLaunchCooperativeKernel((void*)lstm_rec, dim3(128), dim3(512),
                                               args, 0, stream);
    if (ce != hipSuccess) {
      hipLaunchKernelGGL(lstm_rec, dim3(128), dim3(512), 0, stream, a0, a1, a2, a3, a4);
    }
  }
  hipLaunchKernelGGL(dense_kernel, dim3(T_LEN / 4), dim3(256), 0, stream, hout, WT, db, feats);
  hipLaunchKernelGGL(viterbi_fwd, dim3(1), dim3(64), 0, stream, feats, trans, bp, out, best);
  hipLaunchKernelGGL(bt_chunk, dim3(64), dim3(64), 0, stream, bp, mmap);
  hipLaunchKernelGGL(bt_stitch, dim3(1), dim3(64), 0, stream, mmap, best, entry);
  hipLaunchKernelGGL(bt_fill, dim3(64), dim3(64), 0, stream, bp, entry, out);
}